// Round 5
// baseline (78.735 us; speedup 1.0000x reference)
//
#include <hip/hip_runtime.h>
#include <stdint.h>

#define D 128
#define NTHR 256
#define RPB 16  // rows per block: 4 waves x 4 rows

typedef float f2 __attribute__((ext_vector_type(2)));
typedef float f4 __attribute__((ext_vector_type(4)));
typedef __fp16 h2 __attribute__((ext_vector_type(2)));

// ---- d_ws layout (all weights pre-masked) ----
#define WMU_OFF 0                        // uint32[i*64+jp] = {f16 mu[i][2jp], f16 mu[i][2jp+1]}
#define WLS_OFF (D * D * 2)              // 32768: same packing for ls
#define W1T_OFF (WLS_OFF + D * D * 2)    // 65536: f32[i*D+j] = W1[j][i], masked j>i
#define BMU_OFF (W1T_OFF + D * D * 4)    // 131072: f32[D]
#define BLS_OFF (BMU_OFF + D * 4)        // 131584: f32[D]
#define WS_NEED (size_t)(BLS_OFF + D * 4)

__device__ __forceinline__ uint16_t f2h(float f) {
  const __fp16 h = (__fp16)f;  // RNE
  return __builtin_bit_cast(uint16_t, h);
}
__device__ __forceinline__ h2 bch2(uint32_t u) { return __builtin_bit_cast(h2, u); }

__device__ __forceinline__ float fdot2f(h2 a, h2 b, float c) {
#if __has_builtin(__builtin_amdgcn_fdot2)
  return __builtin_amdgcn_fdot2(a, b, c, false);
#else
  return fmaf((float)a[0], (float)b[0], fmaf((float)a[1], (float)b[1], c));
#endif
}

#define DPP_ADD(v, ctrl)                                                          \
  (v) += __int_as_float(__builtin_amdgcn_update_dpp(0, __float_as_int(v), (ctrl), \
                                                    0xf, 0xf, true))
// all-lanes 16-lane butterfly: quad_perm xor1, xor2, row_ror:4, row_ror:8
#define RED16(v)       \
  do {                 \
    DPP_ADD(v, 0xB1);  \
    DPP_ADD(v, 0x4E);  \
    DPP_ADD(v, 0x124); \
    DPP_ADD(v, 0x128); \
  } while (0)

// ================= pre-pass: mask + pack into d_ws =================
__global__ __launch_bounds__(256)
void iaf_prep(const float* __restrict__ W1, const float* __restrict__ Wmu,
              const float* __restrict__ Wls, const float* __restrict__ bmu,
              const float* __restrict__ bls, uint8_t* __restrict__ ws) {
  uint32_t* wmup = (uint32_t*)(ws + WMU_OFF);
  uint32_t* wlsp = (uint32_t*)(ws + WLS_OFF);
  float* w1t = (float*)(ws + W1T_OFF);
  float* bmuw = (float*)(ws + BMU_OFF);
  float* blsw = (float*)(ws + BLS_OFF);
  const int idx = blockIdx.x * 256 + threadIdx.x;
  if (idx < D * D) {
    const int i = idx >> 7, j = idx & (D - 1);
    w1t[idx] = (j > i) ? W1[j * D + i] : 0.f;  // column i of W1, masked
  }
  if (idx < D * D / 2) {
    const int i = idx >> 6, jp = idx & 63;
    const int j0 = jp * 2;
    const float mu0 = (j0 < i) ? Wmu[i * D + j0] : 0.f;
    const float mu1 = (j0 + 1 < i) ? Wmu[i * D + j0 + 1] : 0.f;
    const float ls0 = (j0 < i) ? Wls[i * D + j0] : 0.f;
    const float ls1 = (j0 + 1 < i) ? Wls[i * D + j0 + 1] : 0.f;
    wmup[idx] = (uint32_t)f2h(mu0) | ((uint32_t)f2h(mu1) << 16);
    wlsp[idx] = (uint32_t)f2h(ls0) | ((uint32_t)f2h(ls1) << 16);
  }
  if (idx < D) {
    bmuw[idx] = bmu[idx];
    blsw[idx] = bls[idx];
  }
}

// ================= main: fdot2 dots, distance-4 register prefetch =================
// WM/WL: uint4 (4 dwords = 4 h2 pairs). W1A/W1B: f4 (8 f32 w1 cols).
#define STEP(I, XE, ZRI, WM, WL, W1A, W1B)                          \
  {                                                                 \
    const float bmu_i = bmu_p[(I)];                                 \
    const float bls_i = bls_p[(I)];                                 \
    const f2 h0 = __builtin_elementwise_max(A0, (f2)0.f);           \
    const f2 h1 = __builtin_elementwise_max(A1, (f2)0.f);           \
    const f2 h2_ = __builtin_elementwise_max(A2, (f2)0.f);          \
    const f2 h3 = __builtin_elementwise_max(A3, (f2)0.f);           \
    const h2 hp0 = __builtin_amdgcn_cvt_pkrtz(h0.x, h0.y);          \
    const h2 hp1 = __builtin_amdgcn_cvt_pkrtz(h1.x, h1.y);          \
    const h2 hp2 = __builtin_amdgcn_cvt_pkrtz(h2_.x, h2_.y);        \
    const h2 hp3 = __builtin_amdgcn_cvt_pkrtz(h3.x, h3.y);          \
    float mua = fdot2f(hp0, bch2(WM.x), 0.f);                       \
    float mub = fdot2f(hp1, bch2(WM.y), 0.f);                       \
    mua = fdot2f(hp2, bch2(WM.z), mua);                             \
    mub = fdot2f(hp3, bch2(WM.w), mub);                             \
    float lsa = fdot2f(hp0, bch2(WL.x), 0.f);                       \
    float lsb = fdot2f(hp1, bch2(WL.y), 0.f);                       \
    lsa = fdot2f(hp2, bch2(WL.z), lsa);                             \
    lsb = fdot2f(hp3, bch2(WL.w), lsb);                             \
    float mu_p = mua + mub;                                         \
    float ls_p = lsa + lsb;                                         \
    {                                                               \
      const int pf = ((I) + 4 < D) ? (I) + 4 : D - 1;               \
      WM = *(const uint4*)(wmu_b + pf * 256);                       \
      WL = *(const uint4*)(wls_b + pf * 256);                       \
    }                                                               \
    RED16(mu_p);                                                    \
    RED16(ls_p);                                                    \
    const float mu_t = mu_p + bmu_i;                                \
    const float ls_t = ls_p + bls_i;                                \
    const float zi = fmaf((XE), __expf(ls_t), mu_t);                \
    ldj += ls_t;                                                    \
    if (own) ZRI = zi;                                              \
    f2 zz;                                                          \
    zz.x = zi;                                                      \
    zz.y = zi;                                                      \
    A0 = __builtin_elementwise_fma(zz, W1A.xy, A0);                 \
    A1 = __builtin_elementwise_fma(zz, W1A.zw, A1);                 \
    A2 = __builtin_elementwise_fma(zz, W1B.xy, A2);                 \
    A3 = __builtin_elementwise_fma(zz, W1B.zw, A3);                 \
    {                                                               \
      const int pf = ((I) + 4 < D) ? (I) + 4 : D - 1;               \
      W1A = *(const f4*)(w1t_b + pf * 512);                         \
      W1B = *(const f4*)(w1t_b + pf * 512 + 16);                    \
    }                                                               \
  }

__global__ __launch_bounds__(NTHR, 2)
void iaf_main(const float* __restrict__ x, const float* __restrict__ b1,
              const uint8_t* __restrict__ ws, float* __restrict__ out, int B) {
  const int tid = threadIdx.x;
  const int m = tid & 15;
  const int row = blockIdx.x * RPB + (tid >> 4);

  const float* __restrict__ xp = x + (size_t)row * D;
  const uint8_t* __restrict__ wmu_b = ws + WMU_OFF + m * 16;  // + i*256
  const uint8_t* __restrict__ wls_b = ws + WLS_OFF + m * 16;  // + i*256
  const uint8_t* __restrict__ w1t_b = ws + W1T_OFF + m * 32;  // + i*512
  const float* __restrict__ bmu_p = (const float*)(ws + BMU_OFF);
  const float* __restrict__ bls_p = (const float*)(ws + BLS_OFF);

  f2 A0, A1, A2, A3;  // a[8m..8m+7]
  {
    const f4 t0 = *(const f4*)(b1 + m * 8);
    const f4 t1 = *(const f4*)(b1 + m * 8 + 4);
    A0 = t0.xy; A1 = t0.zw; A2 = t1.xy; A3 = t1.zw;
  }
  float zr0 = 0, zr1 = 0, zr2 = 0, zr3 = 0, zr4 = 0, zr5 = 0, zr6 = 0, zr7 = 0;
  float ldj = 0.f;

  // 4 prefetch sets, distance 4 (set k holds row I with I%4==k)
  uint4 wmS0 = *(const uint4*)(wmu_b);
  uint4 wmS1 = *(const uint4*)(wmu_b + 256);
  uint4 wmS2 = *(const uint4*)(wmu_b + 512);
  uint4 wmS3 = *(const uint4*)(wmu_b + 768);
  uint4 wlS0 = *(const uint4*)(wls_b);
  uint4 wlS1 = *(const uint4*)(wls_b + 256);
  uint4 wlS2 = *(const uint4*)(wls_b + 512);
  uint4 wlS3 = *(const uint4*)(wls_b + 768);
  f4 w1aS0 = *(const f4*)(w1t_b);
  f4 w1bS0 = *(const f4*)(w1t_b + 16);
  f4 w1aS1 = *(const f4*)(w1t_b + 512);
  f4 w1bS1 = *(const f4*)(w1t_b + 512 + 16);
  f4 w1aS2 = *(const f4*)(w1t_b + 1024);
  f4 w1bS2 = *(const f4*)(w1t_b + 1024 + 16);
  f4 w1aS3 = *(const f4*)(w1t_b + 1536);
  f4 w1bS3 = *(const f4*)(w1t_b + 1536 + 16);

  f4 x4a = *(const f4*)(xp);
  f4 x4b;

#pragma unroll 1
  for (int ob = 0; ob < 16; ++ob) {
    const int i0 = ob * 8;
    const bool own = (m == ob);
    x4b = *(const f4*)(xp + i0 + 4);
    STEP(i0 + 0, x4a.x, zr0, wmS0, wlS0, w1aS0, w1bS0);
    STEP(i0 + 1, x4a.y, zr1, wmS1, wlS1, w1aS1, w1bS1);
    STEP(i0 + 2, x4a.z, zr2, wmS2, wlS2, w1aS2, w1bS2);
    STEP(i0 + 3, x4a.w, zr3, wmS3, wlS3, w1aS3, w1bS3);
    x4a = *(const f4*)(xp + ((i0 + 8 < D) ? i0 + 8 : D - 4));
    STEP(i0 + 4, x4b.x, zr4, wmS0, wlS0, w1aS0, w1bS0);
    STEP(i0 + 5, x4b.y, zr5, wmS1, wlS1, w1aS1, w1bS1);
    STEP(i0 + 6, x4b.z, zr6, wmS2, wlS2, w1aS2, w1bS2);
    STEP(i0 + 7, x4b.w, zr7, wmS3, wlS3, w1aS3, w1bS3);
  }

  f4 o0, o1;
  o0.x = zr0; o0.y = zr1; o0.z = zr2; o0.w = zr3;
  o1.x = zr4; o1.y = zr5; o1.z = zr6; o1.w = zr7;
  float* zo = out + (size_t)row * D + m * 8;
  *(f4*)(zo) = o0;
  *(f4*)(zo + 4) = o1;
  if (m == 0) out[(size_t)B * D + row] = ldj;
}

// ================= fallback (proven R3 kernel, if ws too small) =================
#define W1S 136
__device__ __forceinline__ uint16_t f2bf(float f) {
  uint32_t u = __float_as_uint(f);
  u += 0x7fffu + ((u >> 16) & 1u);
  return (uint16_t)(u >> 16);
}
__device__ __forceinline__ f2 unpk(uint32_t u) {
  f2 r;
  r.x = __uint_as_float(u << 16);
  r.y = __uint_as_float(u & 0xffff0000u);
  return r;
}
#define FSTEP(I, XE, ZRE, MKE, WM0, WM1, WL0, WL1)                  \
  {                                                                 \
    const float bmu_i = bmu[(I)];                                   \
    const float bls_i = bls[(I)];                                   \
    const f2 h0 = __builtin_elementwise_max(A0, (f2)0.f);           \
    const f2 h1 = __builtin_elementwise_max(A1, (f2)0.f);           \
    const f2 h2 = __builtin_elementwise_max(A2, (f2)0.f);           \
    const f2 h3 = __builtin_elementwise_max(A3, (f2)0.f);           \
    const f2 q0 = h0 * mk0, q1 = h1 * mk1;                          \
    const f2 q2 = h2 * mk2, q3 = h3 * mk3;                          \
    f2 am = q0 * WM0.xy;                                            \
    f2 al = q0 * WL0.xy;                                            \
    am = __builtin_elementwise_fma(q1, WM0.zw, am);                 \
    al = __builtin_elementwise_fma(q1, WL0.zw, al);                 \
    am = __builtin_elementwise_fma(q2, WM1.xy, am);                 \
    al = __builtin_elementwise_fma(q2, WL1.xy, al);                 \
    am = __builtin_elementwise_fma(q3, WM1.zw, am);                 \
    al = __builtin_elementwise_fma(q3, WL1.zw, al);                 \
    float mu_p = am.x + am.y;                                       \
    float ls_p = al.x + al.y;                                       \
    {                                                               \
      const int pfr = ((I) + 2 < D) ? (I) + 2 : D - 1;              \
      WM0 = *(const f4*)(wmup + pfr * D);                           \
      WM1 = *(const f4*)(wmup + pfr * D + 4);                       \
      WL0 = *(const f4*)(wlsp + pfr * D);                           \
      WL1 = *(const f4*)(wlsp + pfr * D + 4);                       \
    }                                                               \
    RED16(mu_p);                                                    \
    RED16(ls_p);                                                    \
    const float mu_t = mu_p + bmu_i;                                \
    const float ls_t = ls_p + bls_i;                                \
    const float zi = fmaf((XE), __expf(ls_t), mu_t);                \
    ldj += ls_t;                                                    \
    const uint4 wv = *(const uint4*)(w1p + (I)*W1S);                \
    if (own) {                                                      \
      ZRE = zi;                                                     \
      MKE = 1.f;                                                    \
    }                                                               \
    f2 zz;                                                          \
    zz.x = zi;                                                      \
    zz.y = zi;                                                      \
    A0 = __builtin_elementwise_fma(zz, unpk(wv.x), A0);             \
    A1 = __builtin_elementwise_fma(zz, unpk(wv.y), A1);             \
    A2 = __builtin_elementwise_fma(zz, unpk(wv.z), A2);             \
    A3 = __builtin_elementwise_fma(zz, unpk(wv.w), A3);             \
  }

__global__ __launch_bounds__(NTHR, 2)
void iaf_fb(const float* __restrict__ x, const float* __restrict__ W1,
            const float* __restrict__ b1, const float* __restrict__ Wmu,
            const float* __restrict__ bmu, const float* __restrict__ Wls,
            const float* __restrict__ bls, float* __restrict__ out, int B) {
  __shared__ uint16_t w1c[D * W1S];
  const int tid = threadIdx.x;
  for (int idx = tid; idx < D * D; idx += NTHR) {
    const int p = idx >> 7, q = idx & (D - 1);
    w1c[q * W1S + p] = f2bf((p > q) ? W1[idx] : 0.f);
  }
  __syncthreads();
  const int lane = tid & 63;
  const int m = lane & 15;
  const int row = blockIdx.x * RPB + (tid >> 4);
  const float* __restrict__ xp = x + (size_t)row * D;
  const float* __restrict__ wmup = Wmu + m * 8;
  const float* __restrict__ wlsp = Wls + m * 8;
  const uint16_t* __restrict__ w1p = w1c + m * 8;
  f2 A0, A1, A2, A3;
  {
    const f4 t0 = *(const f4*)(b1 + m * 8);
    const f4 t1 = *(const f4*)(b1 + m * 8 + 4);
    A0 = t0.xy; A1 = t0.zw; A2 = t1.xy; A3 = t1.zw;
  }
  f2 mk0 = (f2)0.f, mk1 = (f2)0.f, mk2 = (f2)0.f, mk3 = (f2)0.f;
  float zr0 = 0, zr1 = 0, zr2 = 0, zr3 = 0, zr4 = 0, zr5 = 0, zr6 = 0, zr7 = 0;
  float ldj = 0.f;
  f4 wmA0 = *(const f4*)(wmup);
  f4 wmA1 = *(const f4*)(wmup + 4);
  f4 wlA0 = *(const f4*)(wlsp);
  f4 wlA1 = *(const f4*)(wlsp + 4);
  f4 wmB0 = *(const f4*)(wmup + D);
  f4 wmB1 = *(const f4*)(wmup + D + 4);
  f4 wlB0 = *(const f4*)(wlsp + D);
  f4 wlB1 = *(const f4*)(wlsp + D + 4);
  f4 x4a = *(const f4*)(xp);
  f4 x4b;
  for (int ib = 0; ib < 16; ++ib) {
    const int i0 = ib * 8;
    const bool own = (m == ib);
    x4b = *(const f4*)(xp + i0 + 4);
    FSTEP(i0 + 0, x4a.x, zr0, mk0.x, wmA0, wmA1, wlA0, wlA1);
    FSTEP(i0 + 1, x4a.y, zr1, mk0.y, wmB0, wmB1, wlB0, wlB1);
    FSTEP(i0 + 2, x4a.z, zr2, mk1.x, wmA0, wmA1, wlA0, wlA1);
    FSTEP(i0 + 3, x4a.w, zr3, mk1.y, wmB0, wmB1, wlB0, wlB1);
    {
      const int nx = (i0 + 8 < D) ? i0 + 8 : D - 4;
      x4a = *(const f4*)(xp + nx);
    }
    FSTEP(i0 + 4, x4b.x, zr4, mk2.x, wmA0, wmA1, wlA0, wlA1);
    FSTEP(i0 + 5, x4b.y, zr5, mk2.y, wmB0, wmB1, wlB0, wlB1);
    FSTEP(i0 + 6, x4b.z, zr6, mk3.x, wmA0, wmA1, wlA0, wlA1);
    FSTEP(i0 + 7, x4b.w, zr7, mk3.y, wmB0, wmB1, wlB0, wlB1);
  }
  f4 o0, o1;
  o0.x = zr0; o0.y = zr1; o0.z = zr2; o0.w = zr3;
  o1.x = zr4; o1.y = zr5; o1.z = zr6; o1.w = zr7;
  float* zo = out + (size_t)row * D + m * 8;
  *(f4*)(zo) = o0;
  *(f4*)(zo + 4) = o1;
  if (m == 0) out[(size_t)B * D + row] = ldj;
}

extern "C" void kernel_launch(void* const* d_in, const int* in_sizes, int n_in,
                              void* d_out, int out_size, void* d_ws, size_t ws_size,
                              hipStream_t stream) {
  const float* x   = (const float*)d_in[0];
  const float* W1  = (const float*)d_in[1];
  const float* b1  = (const float*)d_in[2];
  const float* Wmu = (const float*)d_in[3];
  const float* bmu = (const float*)d_in[4];
  const float* Wls = (const float*)d_in[5];
  const float* bls = (const float*)d_in[6];
  float* out = (float*)d_out;

  const int B = in_sizes[0] / D;          // 8192
  const int grid = (B + RPB - 1) / RPB;   // 512

  if (ws_size >= WS_NEED) {
    iaf_prep<<<(D * D + 255) / 256, 256, 0, stream>>>(W1, Wmu, Wls, bmu, bls,
                                                      (uint8_t*)d_ws);
    iaf_main<<<grid, NTHR, 0, stream>>>(x, b1, (const uint8_t*)d_ws, out, B);
  } else {
    iaf_fb<<<grid, NTHR, 0, stream>>>(x, W1, b1, Wmu, bmu, Wls, bls, out, B);
  }
}

// Round 6
// 52.348 us; speedup vs baseline: 1.5041x; 1.5041x over previous
//
#include <hip/hip_runtime.h>
#include <stdint.h>

#define D 128
#define RPB 32      // rows per block (32 lanes per row, 1024 threads, 16 waves)
#define NTHR 1024
#define W1_OFF (D * 512)                  // ws: wml 64KB, then w1t 32KB
#define WS_NEED (size_t)(W1_OFF + D * 256)

typedef float f2 __attribute__((ext_vector_type(2)));
typedef float f4 __attribute__((ext_vector_type(4)));
typedef __fp16 h2 __attribute__((ext_vector_type(2)));

__device__ __forceinline__ uint16_t f2h(float f) {
  const __fp16 h = (__fp16)f;  // RNE
  return __builtin_bit_cast(uint16_t, h);
}
__device__ __forceinline__ uint32_t pkh(float a, float b) {
  return (uint32_t)f2h(a) | ((uint32_t)f2h(b) << 16);
}
__device__ __forceinline__ h2 bch2(uint32_t u) { return __builtin_bit_cast(h2, u); }

__device__ __forceinline__ float fdot2f(h2 a, h2 b, float c) {
#if __has_builtin(__builtin_amdgcn_fdot2)
  return __builtin_amdgcn_fdot2(a, b, c, false);
#else
  return fmaf((float)a[0], (float)b[0], fmaf((float)a[1], (float)b[1], c));
#endif
}

// xor-16 lane exchange within each 32-lane group (BitMode: xor=0x10, and=0x1F)
__device__ __forceinline__ float swz16(float v) {
  return __int_as_float(__builtin_amdgcn_ds_swizzle(__float_as_int(v), 0x401F));
}
__device__ __forceinline__ float rdlane(float v, int l) {
  return __int_as_float(__builtin_amdgcn_readlane(__float_as_int(v), l));
}

#define DPP_ADD(v, ctrl)                                                          \
  (v) += __int_as_float(__builtin_amdgcn_update_dpp(0, __float_as_int(v), (ctrl), \
                                                    0xf, 0xf, true))

// ============ prep: mask + transpose + f16-pack into ws (LDS image) ============
// wml row i (512B): lane m chunk (16B) = {mu(4m,4m+1)},{mu(4m+2,4m+3)},{ls(4m,4m+1)},{ls(4m+2,4m+3)}
// w1t row i (256B): lane m chunk (8B)  = {w1t(4m,4m+1)},{w1t(4m+2,4m+3)}, w1t[i][j]=W1[j][i]
__global__ __launch_bounds__(256)
void iaf_prep(const float* __restrict__ W1, const float* __restrict__ Wmu,
              const float* __restrict__ Wls, uint8_t* __restrict__ ws) {
  const int t = blockIdx.x * 256 + threadIdx.x;
  if (t >= D * 32) return;
  const int i = t >> 5, m = t & 31;
  const int j0 = m * 4;
  const f4 mu = *(const f4*)(Wmu + i * D + j0);
  const f4 ls = *(const f4*)(Wls + i * D + j0);
  const float m0 = (j0 + 0 < i) ? mu.x : 0.f, m1 = (j0 + 1 < i) ? mu.y : 0.f;
  const float m2 = (j0 + 2 < i) ? mu.z : 0.f, m3 = (j0 + 3 < i) ? mu.w : 0.f;
  const float l0 = (j0 + 0 < i) ? ls.x : 0.f, l1 = (j0 + 1 < i) ? ls.y : 0.f;
  const float l2 = (j0 + 2 < i) ? ls.z : 0.f, l3 = (j0 + 3 < i) ? ls.w : 0.f;
  uint4 pk;
  pk.x = pkh(m0, m1);
  pk.y = pkh(m2, m3);
  pk.z = pkh(l0, l1);
  pk.w = pkh(l2, l3);
  *(uint4*)(ws + i * 512 + m * 16) = pk;

  const float w0 = (j0 + 0 > i) ? W1[(j0 + 0) * D + i] : 0.f;
  const float w1 = (j0 + 1 > i) ? W1[(j0 + 1) * D + i] : 0.f;
  const float w2 = (j0 + 2 > i) ? W1[(j0 + 2) * D + i] : 0.f;
  const float w3 = (j0 + 3 > i) ? W1[(j0 + 3) * D + i] : 0.f;
  uint2 p2;
  p2.x = pkh(w0, w1);
  p2.y = pkh(w2, w3);
  *(uint2*)(ws + W1_OFF + i * 256 + m * 8) = p2;
}

// ============ main: 32 lanes/row, LDS f16 weights, folded DPP reduce ============
#define STEP(T, BI, BMUR, BLSR, WM, WV)                                  \
  {                                                                      \
    const f2 h01 = __builtin_elementwise_max(A01, (f2)0.f);              \
    const f2 h23 = __builtin_elementwise_max(A23, (f2)0.f);              \
    const h2 hp01 = __builtin_amdgcn_cvt_pkrtz(h01.x, h01.y);            \
    const h2 hp23 = __builtin_amdgcn_cvt_pkrtz(h23.x, h23.y);            \
    float mu_p = fdot2f(hp01, bch2(WM.x), 0.f);                          \
    mu_p = fdot2f(hp23, bch2(WM.y), mu_p);                               \
    float ls_p = fdot2f(hp01, bch2(WM.z), 0.f);                          \
    ls_p = fdot2f(hp23, bch2(WM.w), ls_p);                               \
    const float mine = hi ? ls_p : mu_p;                                 \
    const float give = hi ? mu_p : ls_p;                                 \
    float fold = mine + swz16(give);                                     \
    DPP_ADD(fold, 0xB1);                                                 \
    DPP_ADD(fold, 0x4E);                                                 \
    DPP_ADD(fold, 0x124);                                                \
    DPP_ADD(fold, 0x128);                                                \
    const float other = swz16(fold);                                     \
    const float mu_t = (hi ? other : fold) + rdlane(BMUR, (BI));         \
    const float ls_t = (hi ? fold : other) + rdlane(BLSR, (BI));         \
    const float zi = fmaf(x4[T], __expf(ls_t), mu_t);                    \
    ldj += ls_t;                                                         \
    if (own) zr[T] = zi;                                                 \
    const f2 w01 = __builtin_convertvector(bch2(WV.x), f2);              \
    const f2 w23 = __builtin_convertvector(bch2(WV.y), f2);              \
    f2 zz;                                                               \
    zz.x = zi;                                                           \
    zz.y = zi;                                                           \
    A01 = __builtin_elementwise_fma(zz, w01, A01);                       \
    A23 = __builtin_elementwise_fma(zz, w23, A23);                       \
  }

__global__ __launch_bounds__(NTHR, 4)
void iaf_main(const float* __restrict__ x, const float* __restrict__ b1,
              const float* __restrict__ bmu, const float* __restrict__ bls,
              const uint8_t* __restrict__ ws, float* __restrict__ out, int B) {
  __shared__ uint4 wml[D][32];                                   // 64KB
  __shared__ uint2 w1t[D][32] __attribute__((aligned(16)));      // 32KB

  const int tid = threadIdx.x;
  // ---- stage LDS (straight copy of prep's image) ----
  {
    const uint4* s1 = (const uint4*)ws;
    uint4* d1 = (uint4*)wml;
#pragma unroll
    for (int k = 0; k < 4; ++k) d1[tid + k * NTHR] = s1[tid + k * NTHR];
    const uint4* s2 = (const uint4*)(ws + W1_OFF);
    uint4* d2 = (uint4*)w1t;
#pragma unroll
    for (int k = 0; k < 2; ++k) d2[tid + k * NTHR] = s2[tid + k * NTHR];
  }

  const int sub = tid & 31;
  const int g = tid >> 5;
  const int row = blockIdx.x * RPB + g;
  const bool hi = (sub & 16) != 0;

  // per-lane bias registers for v_readlane broadcast (lane l holds bias[32r+l])
  const float bmuR0 = bmu[sub], bmuR1 = bmu[32 + sub];
  const float bmuR2 = bmu[64 + sub], bmuR3 = bmu[96 + sub];
  const float blsR0 = bls[sub], blsR1 = bls[32 + sub];
  const float blsR2 = bls[64 + sub], blsR3 = bls[96 + sub];

  const float* __restrict__ xp = x + (size_t)row * D;
  f2 A01, A23;  // a[4*sub .. 4*sub+3]
  {
    const f4 t0 = *(const f4*)(b1 + sub * 4);
    A01.x = t0.x; A01.y = t0.y; A23.x = t0.z; A23.y = t0.w;
  }
  float zr[4] = {0.f, 0.f, 0.f, 0.f};
  float ldj = 0.f;

  __syncthreads();

  f4 x4 = *(const f4*)(xp);  // x[i0..i0+3] for current group

#pragma unroll
  for (int R = 0; R < 4; ++R) {
    const float BM = (R == 0) ? bmuR0 : (R == 1) ? bmuR1 : (R == 2) ? bmuR2 : bmuR3;
    const float BL = (R == 0) ? blsR0 : (R == 1) ? blsR1 : (R == 2) ? blsR2 : blsR3;
#pragma unroll 1
    for (int blk = 0; blk < 8; ++blk) {
      const int i0 = R * 32 + blk * 4;
      const bool own = (sub == (i0 >> 2));
      const f4 x4n = *(const f4*)(xp + ((i0 + 4) & 127));  // next group's x
      const uint4 wm0 = wml[i0 + 0][sub];
      const uint4 wm1 = wml[i0 + 1][sub];
      const uint4 wm2 = wml[i0 + 2][sub];
      const uint4 wm3 = wml[i0 + 3][sub];
      const uint2 wv0 = w1t[i0 + 0][sub];
      const uint2 wv1 = w1t[i0 + 1][sub];
      const uint2 wv2 = w1t[i0 + 2][sub];
      const uint2 wv3 = w1t[i0 + 3][sub];
      STEP(0, blk * 4 + 0, BM, BL, wm0, wv0);
      STEP(1, blk * 4 + 1, BM, BL, wm1, wv1);
      STEP(2, blk * 4 + 2, BM, BL, wm2, wv2);
      STEP(3, blk * 4 + 3, BM, BL, wm3, wv3);
      x4 = x4n;
    }
  }

  f4 o;
  o.x = zr[0]; o.y = zr[1]; o.z = zr[2]; o.w = zr[3];
  *(f4*)(out + (size_t)row * D + sub * 4) = o;
  if (sub == 0) out[(size_t)B * D + row] = ldj;
}

// ============ fallback (proven R3 kernel, if ws too small) ============
#define FNTHR 256
#define FRPB 16
#define W1S 136
__device__ __forceinline__ uint16_t f2bf(float f) {
  uint32_t u = __float_as_uint(f);
  u += 0x7fffu + ((u >> 16) & 1u);
  return (uint16_t)(u >> 16);
}
__device__ __forceinline__ f2 unpk(uint32_t u) {
  f2 r;
  r.x = __uint_as_float(u << 16);
  r.y = __uint_as_float(u & 0xffff0000u);
  return r;
}
#define RED16F(v)      \
  do {                 \
    DPP_ADD(v, 0xB1);  \
    DPP_ADD(v, 0x4E);  \
    DPP_ADD(v, 0x124); \
    DPP_ADD(v, 0x128); \
  } while (0)
#define FSTEP(I, XE, ZRE, MKE, WM0, WM1, WL0, WL1)                  \
  {                                                                 \
    const float bmu_i = bmu[(I)];                                   \
    const float bls_i = bls[(I)];                                   \
    const f2 h0 = __builtin_elementwise_max(A0, (f2)0.f);           \
    const f2 h1 = __builtin_elementwise_max(A1, (f2)0.f);           \
    const f2 h2 = __builtin_elementwise_max(A2, (f2)0.f);           \
    const f2 h3 = __builtin_elementwise_max(A3, (f2)0.f);           \
    const f2 q0 = h0 * mk0, q1 = h1 * mk1;                          \
    const f2 q2 = h2 * mk2, q3 = h3 * mk3;                          \
    f2 am = q0 * WM0.xy;                                            \
    f2 al = q0 * WL0.xy;                                            \
    am = __builtin_elementwise_fma(q1, WM0.zw, am);                 \
    al = __builtin_elementwise_fma(q1, WL0.zw, al);                 \
    am = __builtin_elementwise_fma(q2, WM1.xy, am);                 \
    al = __builtin_elementwise_fma(q2, WL1.xy, al);                 \
    am = __builtin_elementwise_fma(q3, WM1.zw, am);                 \
    al = __builtin_elementwise_fma(q3, WL1.zw, al);                 \
    float mu_p = am.x + am.y;                                       \
    float ls_p = al.x + al.y;                                       \
    {                                                               \
      const int pfr = ((I) + 2 < D) ? (I) + 2 : D - 1;              \
      WM0 = *(const f4*)(wmup + pfr * D);                           \
      WM1 = *(const f4*)(wmup + pfr * D + 4);                       \
      WL0 = *(const f4*)(wlsp + pfr * D);                           \
      WL1 = *(const f4*)(wlsp + pfr * D + 4);                       \
    }                                                               \
    RED16F(mu_p);                                                   \
    RED16F(ls_p);                                                   \
    const float mu_t = mu_p + bmu_i;                                \
    const float ls_t = ls_p + bls_i;                                \
    const float zi = fmaf((XE), __expf(ls_t), mu_t);                \
    ldj += ls_t;                                                    \
    const uint4 wv = *(const uint4*)(w1p + (I)*W1S);                \
    if (own) {                                                      \
      ZRE = zi;                                                     \
      MKE = 1.f;                                                    \
    }                                                               \
    f2 zz;                                                          \
    zz.x = zi;                                                      \
    zz.y = zi;                                                      \
    A0 = __builtin_elementwise_fma(zz, unpk(wv.x), A0);             \
    A1 = __builtin_elementwise_fma(zz, unpk(wv.y), A1);             \
    A2 = __builtin_elementwise_fma(zz, unpk(wv.z), A2);             \
    A3 = __builtin_elementwise_fma(zz, unpk(wv.w), A3);             \
  }

__global__ __launch_bounds__(FNTHR, 2)
void iaf_fb(const float* __restrict__ x, const float* __restrict__ W1,
            const float* __restrict__ b1, const float* __restrict__ Wmu,
            const float* __restrict__ bmu, const float* __restrict__ Wls,
            const float* __restrict__ bls, float* __restrict__ out, int B) {
  __shared__ uint16_t w1c[D * W1S];
  const int tid = threadIdx.x;
  for (int idx = tid; idx < D * D; idx += FNTHR) {
    const int p = idx >> 7, q = idx & (D - 1);
    w1c[q * W1S + p] = f2bf((p > q) ? W1[idx] : 0.f);
  }
  __syncthreads();
  const int lane = tid & 63;
  const int m = lane & 15;
  const int row = blockIdx.x * FRPB + (tid >> 4);
  const float* __restrict__ xp = x + (size_t)row * D;
  const float* __restrict__ wmup = Wmu + m * 8;
  const float* __restrict__ wlsp = Wls + m * 8;
  const uint16_t* __restrict__ w1p = w1c + m * 8;
  f2 A0, A1, A2, A3;
  {
    const f4 t0 = *(const f4*)(b1 + m * 8);
    const f4 t1 = *(const f4*)(b1 + m * 8 + 4);
    A0 = t0.xy; A1 = t0.zw; A2 = t1.xy; A3 = t1.zw;
  }
  f2 mk0 = (f2)0.f, mk1 = (f2)0.f, mk2 = (f2)0.f, mk3 = (f2)0.f;
  float zr0 = 0, zr1 = 0, zr2 = 0, zr3 = 0, zr4 = 0, zr5 = 0, zr6 = 0, zr7 = 0;
  float ldj = 0.f;
  f4 wmA0 = *(const f4*)(wmup);
  f4 wmA1 = *(const f4*)(wmup + 4);
  f4 wlA0 = *(const f4*)(wlsp);
  f4 wlA1 = *(const f4*)(wlsp + 4);
  f4 wmB0 = *(const f4*)(wmup + D);
  f4 wmB1 = *(const f4*)(wmup + D + 4);
  f4 wlB0 = *(const f4*)(wlsp + D);
  f4 wlB1 = *(const f4*)(wlsp + D + 4);
  f4 x4a = *(const f4*)(xp);
  f4 x4b;
  for (int ib = 0; ib < 16; ++ib) {
    const int i0 = ib * 8;
    const bool own = (m == ib);
    x4b = *(const f4*)(xp + i0 + 4);
    FSTEP(i0 + 0, x4a.x, zr0, mk0.x, wmA0, wmA1, wlA0, wlA1);
    FSTEP(i0 + 1, x4a.y, zr1, mk0.y, wmB0, wmB1, wlB0, wlB1);
    FSTEP(i0 + 2, x4a.z, zr2, mk1.x, wmA0, wmA1, wlA0, wlA1);
    FSTEP(i0 + 3, x4a.w, zr3, mk1.y, wmB0, wmB1, wlB0, wlB1);
    {
      const int nx = (i0 + 8 < D) ? i0 + 8 : D - 4;
      x4a = *(const f4*)(xp + nx);
    }
    FSTEP(i0 + 4, x4b.x, zr4, mk2.x, wmA0, wmA1, wlA0, wlA1);
    FSTEP(i0 + 5, x4b.y, zr5, mk2.y, wmB0, wmB1, wlB0, wlB1);
    FSTEP(i0 + 6, x4b.z, zr6, mk3.x, wmA0, wmA1, wlA0, wlA1);
    FSTEP(i0 + 7, x4b.w, zr7, mk3.y, wmB0, wmB1, wlB0, wlB1);
  }
  f4 o0, o1;
  o0.x = zr0; o0.y = zr1; o0.z = zr2; o0.w = zr3;
  o1.x = zr4; o1.y = zr5; o1.z = zr6; o1.w = zr7;
  float* zo = out + (size_t)row * D + m * 8;
  *(f4*)(zo) = o0;
  *(f4*)(zo + 4) = o1;
  if (m == 0) out[(size_t)B * D + row] = ldj;
}

extern "C" void kernel_launch(void* const* d_in, const int* in_sizes, int n_in,
                              void* d_out, int out_size, void* d_ws, size_t ws_size,
                              hipStream_t stream) {
  const float* x   = (const float*)d_in[0];
  const float* W1  = (const float*)d_in[1];
  const float* b1  = (const float*)d_in[2];
  const float* Wmu = (const float*)d_in[3];
  const float* bmu = (const float*)d_in[4];
  const float* Wls = (const float*)d_in[5];
  const float* bls = (const float*)d_in[6];
  float* out = (float*)d_out;

  const int B = in_sizes[0] / D;  // 8192

  if (ws_size >= WS_NEED) {
    iaf_prep<<<(D * 32 + 255) / 256, 256, 0, stream>>>(W1, Wmu, Wls, (uint8_t*)d_ws);
    const int grid = (B + RPB - 1) / RPB;  // 256
    iaf_main<<<grid, NTHR, 0, stream>>>(x, b1, bmu, bls, (const uint8_t*)d_ws, out, B);
  } else {
    const int grid = (B + FRPB - 1) / FRPB;  // 512
    iaf_fb<<<grid, FNTHR, 0, stream>>>(x, W1, b1, Wmu, bmu, Wls, bls, out, B);
  }
}

// Round 8
// 40.838 us; speedup vs baseline: 1.9280x; 1.2819x over previous
//
#include <hip/hip_runtime.h>
#include <stdint.h>

#define D 128
#define NTHR 512
#define RPB 32  // rows per block: 8 waves x 4 rows(16 lanes each)

typedef float f2 __attribute__((ext_vector_type(2)));
typedef float f4 __attribute__((ext_vector_type(4)));
typedef __fp16 h2 __attribute__((ext_vector_type(2)));

// ws layout (uint16 elements): wmu[D*D] | wls[D*D] | w1t[D*D]
#define WS_NEED (size_t)(D * D * 6)

__device__ __forceinline__ h2 bch2(uint32_t u) { return __builtin_bit_cast(h2, u); }
__device__ __forceinline__ float fdot2f(h2 a, h2 b, float c) {
  return __builtin_amdgcn_fdot2(a, b, c, false);
}
template <int CTRL>
__device__ __forceinline__ float dppmov(float v) {
  return __int_as_float(
      __builtin_amdgcn_update_dpp(0, __float_as_int(v), CTRL, 0xf, 0xf, true));
}
#define DPP_ADD(v, ctrl) (v) += dppmov<(ctrl)>((v))

// ================= prep: mask + transpose + f16-pack into ws =================
__global__ __launch_bounds__(256)
void iaf_prep(const float* __restrict__ W1, const float* __restrict__ Wmu,
              const float* __restrict__ Wls, uint16_t* __restrict__ ws) {
  const int idx = blockIdx.x * 256 + threadIdx.x;
  if (idx >= D * D) return;
  const int i = idx >> 7, j = idx & (D - 1);
  const __fp16 mu = (__fp16)((j < i) ? Wmu[idx] : 0.f);
  const __fp16 ls = (__fp16)((j < i) ? Wls[idx] : 0.f);
  const __fp16 w1 = (__fp16)((j > i) ? W1[j * D + i] : 0.f);  // column i of W1
  ws[idx] = __builtin_bit_cast(uint16_t, mu);
  ws[D * D + idx] = __builtin_bit_cast(uint16_t, ls);
  ws[2 * D * D + idx] = __builtin_bit_cast(uint16_t, w1);
}

// ================= main: 16 lanes/row, f16 LDS weights, all-DPP reduce =================
#define STEP(K)                                                          \
  {                                                                      \
    const int i = i0 + (K);                                              \
    float mu_p = 0.f, ls_p = 0.f;                                        \
    if (m8 < i) { /* lane's wmu/wls chunk has unmasked entries */        \
      const uint4 wmv = *(const uint4*)(wmu_s + i * D + m8);             \
      const uint4 wlv = *(const uint4*)(wls_s + i * D + m8);             \
      const h2 h01 = __builtin_elementwise_max(a01, hz);                 \
      const h2 h23 = __builtin_elementwise_max(a23, hz);                 \
      const h2 h45 = __builtin_elementwise_max(a45, hz);                 \
      const h2 h67 = __builtin_elementwise_max(a67, hz);                 \
      mu_p = fdot2f(h01, bch2(wmv.x), 0.f);                              \
      mu_p = fdot2f(h23, bch2(wmv.y), mu_p);                             \
      mu_p = fdot2f(h45, bch2(wmv.z), mu_p);                             \
      mu_p = fdot2f(h67, bch2(wmv.w), mu_p);                             \
      ls_p = fdot2f(h01, bch2(wlv.x), 0.f);                              \
      ls_p = fdot2f(h23, bch2(wlv.y), ls_p);                             \
      ls_p = fdot2f(h45, bch2(wlv.z), ls_p);                             \
      ls_p = fdot2f(h67, bch2(wlv.w), ls_p);                             \
    }                                                                    \
    /* folded all-lanes reduce within the 16-lane group (pure DPP):      \
       lanes 0-7 accumulate mu, lanes 8-15 accumulate ls */              \
    float fold = hi ? ls_p : mu_p;                                       \
    fold += dppmov<0x128>(hi ? mu_p : ls_p); /* row_ror:8 == xor 8 */    \
    DPP_ADD(fold, 0xB1);  /* quad_perm xor1 */                           \
    DPP_ADD(fold, 0x4E);  /* quad_perm xor2 */                           \
    DPP_ADD(fold, 0x141); /* row_half_mirror: + other quad in half */    \
    const float other = dppmov<0x128>(fold);                             \
    const float mu_t = (hi ? other : fold) + bmu[i];                     \
    const float ls_t = (hi ? fold : other) + bls[i];                     \
    const float ziv = fmaf(xr[K], __expf(ls_t), mu_t); /* owner valid */ \
    const float zi = __int_as_float(                                     \
        __builtin_amdgcn_ds_bpermute(bpi, __float_as_int(ziv)));         \
    ldj += ls_t;                                                         \
    if (own) zr[K] = ziv;                                                \
    if (m8 + 7 > i) { /* lane's w1 chunk has unmasked entries */         \
      const uint4 w1v = *(const uint4*)(w1t_s + i * D + m8);             \
      const h2 z2 = __builtin_amdgcn_cvt_pkrtz(zi, zi);                  \
      a01 = __builtin_elementwise_fma(z2, bch2(w1v.x), a01);             \
      a23 = __builtin_elementwise_fma(z2, bch2(w1v.y), a23);             \
      a45 = __builtin_elementwise_fma(z2, bch2(w1v.z), a45);             \
      a67 = __builtin_elementwise_fma(z2, bch2(w1v.w), a67);             \
    }                                                                    \
  }

__global__ __launch_bounds__(NTHR, 1)
void iaf_main(const float* __restrict__ x, const float* __restrict__ b1,
              const float* __restrict__ bmu, const float* __restrict__ bls,
              const uint16_t* __restrict__ ws, float* __restrict__ out, int B) {
  __shared__ uint16_t wmu_s[D * D];  // 32KB each, 96KB total
  __shared__ uint16_t wls_s[D * D];
  __shared__ uint16_t w1t_s[D * D];

  const int tid = threadIdx.x;
  // ---- stage weights ws -> LDS (b128 copies) ----
  {
    const uint4* s0 = (const uint4*)(ws);
    const uint4* s1 = (const uint4*)(ws + D * D);
    const uint4* s2 = (const uint4*)(ws + 2 * D * D);
    uint4* d0 = (uint4*)wmu_s;
    uint4* d1 = (uint4*)wls_s;
    uint4* d2 = (uint4*)w1t_s;
#pragma unroll
    for (int k = 0; k < 4; ++k) {
      d0[tid + k * NTHR] = s0[tid + k * NTHR];
      d1[tid + k * NTHR] = s1[tid + k * NTHR];
      d2[tid + k * NTHR] = s2[tid + k * NTHR];
    }
  }

  const int m = tid & 15;
  const int m8 = m << 3;
  const bool hi = (m & 8) != 0;
  const int row = blockIdx.x * RPB + (tid >> 4);
  const int bpi0 = (tid & 48) << 2;  // (wave-lane & ~15)*4 base for bpermute

  // lane-resident x chunk: x[row][8m..8m+7]
  const float* __restrict__ xp = x + (size_t)row * D;
  float xr[8];
  {
    const f4 t0 = *(const f4*)(xp + m8);
    const f4 t1 = *(const f4*)(xp + m8 + 4);
    xr[0] = t0.x; xr[1] = t0.y; xr[2] = t0.z; xr[3] = t0.w;
    xr[4] = t1.x; xr[5] = t1.y; xr[6] = t1.z; xr[7] = t1.w;
  }
  // a = b1 chunk, in f16 pairs
  h2 a01, a23, a45, a67;
  {
    const f4 t0 = *(const f4*)(b1 + m8);
    const f4 t1 = *(const f4*)(b1 + m8 + 4);
    a01 = __builtin_amdgcn_cvt_pkrtz(t0.x, t0.y);
    a23 = __builtin_amdgcn_cvt_pkrtz(t0.z, t0.w);
    a45 = __builtin_amdgcn_cvt_pkrtz(t1.x, t1.y);
    a67 = __builtin_amdgcn_cvt_pkrtz(t1.z, t1.w);
  }
  const h2 hz = bch2(0u);
  float zr[8];
  float ldj = 0.f;

  __syncthreads();

#pragma unroll 1
  for (int ob = 0; ob < 16; ++ob) {
    const int i0 = ob * 8;
    const bool own = (m == ob);
    const int bpi = bpi0 | (ob << 2);
    STEP(0)
    STEP(1)
    STEP(2)
    STEP(3)
    STEP(4)
    STEP(5)
    STEP(6)
    STEP(7)
  }

  // ---- stores: lane m owns columns 8m..8m+7 of its row ----
  f4 o0, o1;
  o0.x = zr[0]; o0.y = zr[1]; o0.z = zr[2]; o0.w = zr[3];
  o1.x = zr[4]; o1.y = zr[5]; o1.z = zr[6]; o1.w = zr[7];
  float* zo = out + (size_t)row * D + m8;
  *(f4*)(zo) = o0;
  *(f4*)(zo + 4) = o1;
  if (m == 0) out[(size_t)B * D + row] = ldj;
}

// ================= fallback (proven R3 kernel, if ws too small) =================
#define FNTHR 256
#define FRPB 16
#define W1S 136
__device__ __forceinline__ uint16_t f2bf(float f) {
  uint32_t u = __float_as_uint(f);
  u += 0x7fffu + ((u >> 16) & 1u);
  return (uint16_t)(u >> 16);
}
__device__ __forceinline__ f2 unpk(uint32_t u) {
  f2 r;
  r.x = __uint_as_float(u << 16);
  r.y = __uint_as_float(u & 0xffff0000u);
  return r;
}
#define RED16F(v)      \
  do {                 \
    DPP_ADD(v, 0xB1);  \
    DPP_ADD(v, 0x4E);  \
    DPP_ADD(v, 0x124); \
    DPP_ADD(v, 0x128); \
  } while (0)
#define FSTEP(I, XE, ZRE, MKE, WM0, WM1, WL0, WL1)                  \
  {                                                                 \
    const float bmu_i = bmu[(I)];                                   \
    const float bls_i = bls[(I)];                                   \
    const f2 h0 = __builtin_elementwise_max(A0, (f2)0.f);           \
    const f2 h1 = __builtin_elementwise_max(A1, (f2)0.f);           \
    const f2 h2_ = __builtin_elementwise_max(A2, (f2)0.f);          \
    const f2 h3 = __builtin_elementwise_max(A3, (f2)0.f);           \
    const f2 q0 = h0 * mk0, q1 = h1 * mk1;                          \
    const f2 q2 = h2_ * mk2, q3 = h3 * mk3;                         \
    f2 am = q0 * WM0.xy;                                            \
    f2 al = q0 * WL0.xy;                                            \
    am = __builtin_elementwise_fma(q1, WM0.zw, am);                 \
    al = __builtin_elementwise_fma(q1, WL0.zw, al);                 \
    am = __builtin_elementwise_fma(q2, WM1.xy, am);                 \
    al = __builtin_elementwise_fma(q2, WL1.xy, al);                 \
    am = __builtin_elementwise_fma(q3, WM1.zw, am);                 \
    al = __builtin_elementwise_fma(q3, WL1.zw, al);                 \
    float mu_p = am.x + am.y;                                       \
    float ls_p = al.x + al.y;                                       \
    {                                                               \
      const int pfr = ((I) + 2 < D) ? (I) + 2 : D - 1;              \
      WM0 = *(const f4*)(wmup + pfr * D);                           \
      WM1 = *(const f4*)(wmup + pfr * D + 4);                       \
      WL0 = *(const f4*)(wlsp + pfr * D);                           \
      WL1 = *(const f4*)(wlsp + pfr * D + 4);                       \
    }                                                               \
    RED16F(mu_p);                                                   \
    RED16F(ls_p);                                                   \
    const float mu_t = mu_p + bmu_i;                                \
    const float ls_t = ls_p + bls_i;                                \
    const float zi = fmaf((XE), __expf(ls_t), mu_t);                \
    ldj += ls_t;                                                    \
    const uint4 wv = *(const uint4*)(w1p + (I)*W1S);                \
    if (own) {                                                      \
      ZRE = zi;                                                     \
      MKE = 1.f;                                                    \
    }                                                               \
    f2 zz;                                                          \
    zz.x = zi;                                                      \
    zz.y = zi;                                                      \
    A0 = __builtin_elementwise_fma(zz, unpk(wv.x), A0);             \
    A1 = __builtin_elementwise_fma(zz, unpk(wv.y), A1);             \
    A2 = __builtin_elementwise_fma(zz, unpk(wv.z), A2);             \
    A3 = __builtin_elementwise_fma(zz, unpk(wv.w), A3);             \
  }

__global__ __launch_bounds__(FNTHR, 2)
void iaf_fb(const float* __restrict__ x, const float* __restrict__ W1,
            const float* __restrict__ b1, const float* __restrict__ Wmu,
            const float* __restrict__ bmu, const float* __restrict__ Wls,
            const float* __restrict__ bls, float* __restrict__ out, int B) {
  __shared__ uint16_t w1c[D * W1S];
  const int tid = threadIdx.x;
  for (int idx = tid; idx < D * D; idx += FNTHR) {
    const int p = idx >> 7, q = idx & (D - 1);
    w1c[q * W1S + p] = f2bf((p > q) ? W1[idx] : 0.f);
  }
  __syncthreads();
  const int lane = tid & 63;
  const int m = lane & 15;
  const int row = blockIdx.x * FRPB + (tid >> 4);
  const float* __restrict__ xp = x + (size_t)row * D;
  const float* __restrict__ wmup = Wmu + m * 8;
  const float* __restrict__ wlsp = Wls + m * 8;
  const uint16_t* __restrict__ w1p = w1c + m * 8;
  f2 A0, A1, A2, A3;
  {
    const f4 t0 = *(const f4*)(b1 + m * 8);
    const f4 t1 = *(const f4*)(b1 + m * 8 + 4);
    A0 = t0.xy; A1 = t0.zw; A2 = t1.xy; A3 = t1.zw;
  }
  f2 mk0 = (f2)0.f, mk1 = (f2)0.f, mk2 = (f2)0.f, mk3 = (f2)0.f;
  float zr0 = 0, zr1 = 0, zr2 = 0, zr3 = 0, zr4 = 0, zr5 = 0, zr6 = 0, zr7 = 0;
  float ldj = 0.f;
  f4 wmA0 = *(const f4*)(wmup);
  f4 wmA1 = *(const f4*)(wmup + 4);
  f4 wlA0 = *(const f4*)(wlsp);
  f4 wlA1 = *(const f4*)(wlsp + 4);
  f4 wmB0 = *(const f4*)(wmup + D);
  f4 wmB1 = *(const f4*)(wmup + D + 4);
  f4 wlB0 = *(const f4*)(wlsp + D);
  f4 wlB1 = *(const f4*)(wlsp + D + 4);
  f4 x4a = *(const f4*)(xp);
  f4 x4b;
  for (int ib = 0; ib < 16; ++ib) {
    const int i0 = ib * 8;
    const bool own = (m == ib);
    x4b = *(const f4*)(xp + i0 + 4);
    FSTEP(i0 + 0, x4a.x, zr0, mk0.x, wmA0, wmA1, wlA0, wlA1);
    FSTEP(i0 + 1, x4a.y, zr1, mk0.y, wmB0, wmB1, wlB0, wlB1);
    FSTEP(i0 + 2, x4a.z, zr2, mk1.x, wmA0, wmA1, wlA0, wlA1);
    FSTEP(i0 + 3, x4a.w, zr3, mk1.y, wmB0, wmB1, wlB0, wlB1);
    {
      const int nx = (i0 + 8 < D) ? i0 + 8 : D - 4;
      x4a = *(const f4*)(xp + nx);
    }
    FSTEP(i0 + 4, x4b.x, zr4, mk2.x, wmA0, wmA1, wlA0, wlA1);
    FSTEP(i0 + 5, x4b.y, zr5, mk2.y, wmB0, wmB1, wlB0, wlB1);
    FSTEP(i0 + 6, x4b.z, zr6, mk3.x, wmA0, wmA1, wlA0, wlA1);
    FSTEP(i0 + 7, x4b.w, zr7, mk3.y, wmB0, wmB1, wlB0, wlB1);
  }
  f4 o0, o1;
  o0.x = zr0; o0.y = zr1; o0.z = zr2; o0.w = zr3;
  o1.x = zr4; o1.y = zr5; o1.z = zr6; o1.w = zr7;
  float* zo = out + (size_t)row * D + m * 8;
  *(f4*)(zo) = o0;
  *(f4*)(zo + 4) = o1;
  if (m == 0) out[(size_t)B * D + row] = ldj;
}

extern "C" void kernel_launch(void* const* d_in, const int* in_sizes, int n_in,
                              void* d_out, int out_size, void* d_ws, size_t ws_size,
                              hipStream_t stream) {
  const float* x   = (const float*)d_in[0];
  const float* W1  = (const float*)d_in[1];
  const float* b1  = (const float*)d_in[2];
  const float* Wmu = (const float*)d_in[3];
  const float* bmu = (const float*)d_in[4];
  const float* Wls = (const float*)d_in[5];
  const float* bls = (const float*)d_in[6];
  float* out = (float*)d_out;

  const int B = in_sizes[0] / D;  // 8192

  if (ws_size >= WS_NEED) {
    iaf_prep<<<(D * D + 255) / 256, 256, 0, stream>>>(W1, Wmu, Wls, (uint16_t*)d_ws);
    const int grid = (B + RPB - 1) / RPB;  // 256
    iaf_main<<<grid, NTHR, 0, stream>>>(x, b1, bmu, bls, (const uint16_t*)d_ws, out, B);
  } else {
    const int grid = (B + FRPB - 1) / FRPB;  // 512
    iaf_fb<<<grid, FNTHR, 0, stream>>>(x, W1, b1, Wmu, bmu, Wls, bls, out, B);
  }
}

// Round 9
// 40.312 us; speedup vs baseline: 1.9532x; 1.0130x over previous
//
#include <hip/hip_runtime.h>
#include <stdint.h>

#define D 128
#define NTHR 512
#define RPB 32  // rows per block: 8 waves x 4 rows(16 lanes each)

typedef float f2 __attribute__((ext_vector_type(2)));
typedef float f4 __attribute__((ext_vector_type(4)));
typedef __fp16 h2 __attribute__((ext_vector_type(2)));

// ws layout (uint16 elements): wmu[D*D] | wls[D*D] | w1t[D*D]
#define WS_NEED (size_t)(D * D * 6)

__device__ __forceinline__ h2 bch2(uint32_t u) { return __builtin_bit_cast(h2, u); }
__device__ __forceinline__ float fdot2f(h2 a, h2 b, float c) {
  return __builtin_amdgcn_fdot2(a, b, c, false);
}
template <int CTRL>
__device__ __forceinline__ float dppmov(float v) {
  return __int_as_float(
      __builtin_amdgcn_update_dpp(0, __float_as_int(v), CTRL, 0xf, 0xf, true));
}
#define DPP_ADD(v, ctrl) (v) += dppmov<(ctrl)>((v))

// ================= prep: mask + transpose + f16-pack into ws =================
__global__ __launch_bounds__(256)
void iaf_prep(const float* __restrict__ W1, const float* __restrict__ Wmu,
              const float* __restrict__ Wls, uint16_t* __restrict__ ws) {
  const int idx = blockIdx.x * 256 + threadIdx.x;
  if (idx >= D * D) return;
  const int i = idx >> 7, j = idx & (D - 1);
  const __fp16 mu = (__fp16)((j < i) ? Wmu[idx] : 0.f);
  const __fp16 ls = (__fp16)((j < i) ? Wls[idx] : 0.f);
  const __fp16 w1 = (__fp16)((j > i) ? W1[j * D + i] : 0.f);  // column i of W1
  ws[idx] = __builtin_bit_cast(uint16_t, mu);
  ws[D * D + idx] = __builtin_bit_cast(uint16_t, ls);
  ws[2 * D * D + idx] = __builtin_bit_cast(uint16_t, w1);
}

// ===== main: 16 lanes/row, f16 LDS weights, all-DPP reduce, NO cross-lane on chain =====
#define STEP(K)                                                          \
  {                                                                      \
    const int i = i0 + (K);                                              \
    float mu_p = 0.f, ls_p = 0.f;                                        \
    if (m8 < i) { /* lane's wmu/wls chunk has unmasked entries */        \
      const uint4 wmv = *(const uint4*)(wmu_s + i * D + m8);             \
      const uint4 wlv = *(const uint4*)(wls_s + i * D + m8);             \
      const h2 h01 = __builtin_elementwise_max(a01, hz);                 \
      const h2 h23 = __builtin_elementwise_max(a23, hz);                 \
      const h2 h45 = __builtin_elementwise_max(a45, hz);                 \
      const h2 h67 = __builtin_elementwise_max(a67, hz);                 \
      mu_p = fdot2f(h01, bch2(wmv.x), 0.f);                              \
      mu_p = fdot2f(h23, bch2(wmv.y), mu_p);                             \
      mu_p = fdot2f(h45, bch2(wmv.z), mu_p);                             \
      mu_p = fdot2f(h67, bch2(wmv.w), mu_p);                             \
      ls_p = fdot2f(h01, bch2(wlv.x), 0.f);                              \
      ls_p = fdot2f(h23, bch2(wlv.y), ls_p);                             \
      ls_p = fdot2f(h45, bch2(wlv.z), ls_p);                             \
      ls_p = fdot2f(h67, bch2(wlv.w), ls_p);                             \
    }                                                                    \
    /* folded all-lanes reduce within 16-lane group (pure DPP):          \
       lanes 0-7 carry mu, lanes 8-15 carry ls */                        \
    float fold = hi ? ls_p : mu_p;                                       \
    fold += dppmov<0x128>(hi ? mu_p : ls_p); /* row_ror:8 == xor 8 */    \
    DPP_ADD(fold, 0xB1);  /* quad_perm xor1 */                           \
    DPP_ADD(fold, 0x4E);  /* quad_perm xor2 */                           \
    DPP_ADD(fold, 0x141); /* row_half_mirror */                          \
    const float other = dppmov<0x128>(fold);                             \
    const float mu_t = (hi ? other : fold) + bmu[i];                     \
    const float ls_t = (hi ? fold : other) + bls[i];                     \
    const float zi = fmaf(xs_row[i], __expf(ls_t), mu_t); /* all lanes */\
    ldj += ls_t;                                                         \
    if (own) zr[K] = zi;                                                 \
    if (m8 + 7 > i) { /* lane's w1 chunk has unmasked entries */         \
      const uint4 w1v = *(const uint4*)(w1t_s + i * D + m8);             \
      const h2 z2 = __builtin_amdgcn_cvt_pkrtz(zi, zi);                  \
      a01 = __builtin_elementwise_fma(z2, bch2(w1v.x), a01);             \
      a23 = __builtin_elementwise_fma(z2, bch2(w1v.y), a23);             \
      a45 = __builtin_elementwise_fma(z2, bch2(w1v.z), a45);             \
      a67 = __builtin_elementwise_fma(z2, bch2(w1v.w), a67);             \
    }                                                                    \
  }

__global__ __launch_bounds__(NTHR, 1)
void iaf_main(const float* __restrict__ x, const float* __restrict__ b1,
              const float* __restrict__ bmu, const float* __restrict__ bls,
              const uint16_t* __restrict__ ws, float* __restrict__ out, int B) {
  __shared__ uint16_t wmu_s[D * D];  // 32KB each
  __shared__ uint16_t wls_s[D * D];
  __shared__ uint16_t w1t_s[D * D];
  __shared__ float xs[RPB][D + 1];   // 16.5KB, padded: group addrs hit distinct banks

  const int tid = threadIdx.x;
  const int r0 = blockIdx.x * RPB;
  // ---- stage weights ws -> LDS (b128 copies) ----
  {
    const uint4* s0 = (const uint4*)(ws);
    const uint4* s1 = (const uint4*)(ws + D * D);
    const uint4* s2 = (const uint4*)(ws + 2 * D * D);
    uint4* d0 = (uint4*)wmu_s;
    uint4* d1 = (uint4*)wls_s;
    uint4* d2 = (uint4*)w1t_s;
#pragma unroll
    for (int k = 0; k < 4; ++k) {
      d0[tid + k * NTHR] = s0[tid + k * NTHR];
      d1[tid + k * NTHR] = s1[tid + k * NTHR];
      d2[tid + k * NTHR] = s2[tid + k * NTHR];
    }
  }
  // ---- stage x rows (coalesced global reads, padded LDS rows) ----
  {
    const int r = tid >> 4;          // 0..31
    const int c = (tid & 15) * 8;    // 8 floats per thread
    const f4 t0 = *(const f4*)(x + (size_t)(r0 + r) * D + c);
    const f4 t1 = *(const f4*)(x + (size_t)(r0 + r) * D + c + 4);
    *(f4*)(&xs[r][c]) = t0;
    *(f4*)(&xs[r][c + 4]) = t1;
  }

  const int m = tid & 15;
  const int m8 = m << 3;
  const bool hi = (m & 8) != 0;
  const int row = r0 + (tid >> 4);
  const float* __restrict__ xs_row = xs[tid >> 4];

  // a = b1 chunk, in f16 pairs
  h2 a01, a23, a45, a67;
  {
    const f4 t0 = *(const f4*)(b1 + m8);
    const f4 t1 = *(const f4*)(b1 + m8 + 4);
    a01 = __builtin_amdgcn_cvt_pkrtz(t0.x, t0.y);
    a23 = __builtin_amdgcn_cvt_pkrtz(t0.z, t0.w);
    a45 = __builtin_amdgcn_cvt_pkrtz(t1.x, t1.y);
    a67 = __builtin_amdgcn_cvt_pkrtz(t1.z, t1.w);
  }
  const h2 hz = bch2(0u);
  float zr[8];
  float ldj = 0.f;

  __syncthreads();

#pragma unroll 1
  for (int ob = 0; ob < 16; ++ob) {
    const int i0 = ob * 8;
    const bool own = (m == ob);
    STEP(0)
    STEP(1)
    STEP(2)
    STEP(3)
    STEP(4)
    STEP(5)
    STEP(6)
    STEP(7)
  }

  // ---- stores: lane m owns columns 8m..8m+7 of its row ----
  f4 o0, o1;
  o0.x = zr[0]; o0.y = zr[1]; o0.z = zr[2]; o0.w = zr[3];
  o1.x = zr[4]; o1.y = zr[5]; o1.z = zr[6]; o1.w = zr[7];
  float* zo = out + (size_t)row * D + m8;
  *(f4*)(zo) = o0;
  *(f4*)(zo + 4) = o1;
  if (m == 0) out[(size_t)B * D + row] = ldj;
}

// ================= fallback (proven R3 kernel, if ws too small) =================
#define FNTHR 256
#define FRPB 16
#define W1S 136
__device__ __forceinline__ uint16_t f2bf(float f) {
  uint32_t u = __float_as_uint(f);
  u += 0x7fffu + ((u >> 16) & 1u);
  return (uint16_t)(u >> 16);
}
__device__ __forceinline__ f2 unpk(uint32_t u) {
  f2 r;
  r.x = __uint_as_float(u << 16);
  r.y = __uint_as_float(u & 0xffff0000u);
  return r;
}
#define RED16F(v)      \
  do {                 \
    DPP_ADD(v, 0xB1);  \
    DPP_ADD(v, 0x4E);  \
    DPP_ADD(v, 0x124); \
    DPP_ADD(v, 0x128); \
  } while (0)
#define FSTEP(I, XE, ZRE, MKE, WM0, WM1, WL0, WL1)                  \
  {                                                                 \
    const float bmu_i = bmu[(I)];                                   \
    const float bls_i = bls[(I)];                                   \
    const f2 h0 = __builtin_elementwise_max(A0, (f2)0.f);           \
    const f2 h1 = __builtin_elementwise_max(A1, (f2)0.f);           \
    const f2 h2_ = __builtin_elementwise_max(A2, (f2)0.f);          \
    const f2 h3 = __builtin_elementwise_max(A3, (f2)0.f);           \
    const f2 q0 = h0 * mk0, q1 = h1 * mk1;                          \
    const f2 q2 = h2_ * mk2, q3 = h3 * mk3;                         \
    f2 am = q0 * WM0.xy;                                            \
    f2 al = q0 * WL0.xy;                                            \
    am = __builtin_elementwise_fma(q1, WM0.zw, am);                 \
    al = __builtin_elementwise_fma(q1, WL0.zw, al);                 \
    am = __builtin_elementwise_fma(q2, WM1.xy, am);                 \
    al = __builtin_elementwise_fma(q2, WL1.xy, al);                 \
    am = __builtin_elementwise_fma(q3, WM1.zw, am);                 \
    al = __builtin_elementwise_fma(q3, WL1.zw, al);                 \
    float mu_p = am.x + am.y;                                       \
    float ls_p = al.x + al.y;                                       \
    {                                                               \
      const int pfr = ((I) + 2 < D) ? (I) + 2 : D - 1;              \
      WM0 = *(const f4*)(wmup + pfr * D);                           \
      WM1 = *(const f4*)(wmup + pfr * D + 4);                       \
      WL0 = *(const f4*)(wlsp + pfr * D);                           \
      WL1 = *(const f4*)(wlsp + pfr * D + 4);                       \
    }                                                               \
    RED16F(mu_p);                                                   \
    RED16F(ls_p);                                                   \
    const float mu_t = mu_p + bmu_i;                                \
    const float ls_t = ls_p + bls_i;                                \
    const float zi = fmaf((XE), __expf(ls_t), mu_t);                \
    ldj += ls_t;                                                    \
    const uint4 wv = *(const uint4*)(w1p + (I)*W1S);                \
    if (own) {                                                      \
      ZRE = zi;                                                     \
      MKE = 1.f;                                                    \
    }                                                               \
    f2 zz;                                                          \
    zz.x = zi;                                                      \
    zz.y = zi;                                                      \
    A0 = __builtin_elementwise_fma(zz, unpk(wv.x), A0);             \
    A1 = __builtin_elementwise_fma(zz, unpk(wv.y), A1);             \
    A2 = __builtin_elementwise_fma(zz, unpk(wv.z), A2);             \
    A3 = __builtin_elementwise_fma(zz, unpk(wv.w), A3);             \
  }

__global__ __launch_bounds__(FNTHR, 2)
void iaf_fb(const float* __restrict__ x, const float* __restrict__ W1,
            const float* __restrict__ b1, const float* __restrict__ Wmu,
            const float* __restrict__ bmu, const float* __restrict__ Wls,
            const float* __restrict__ bls, float* __restrict__ out, int B) {
  __shared__ uint16_t w1c[D * W1S];
  const int tid = threadIdx.x;
  for (int idx = tid; idx < D * D; idx += FNTHR) {
    const int p = idx >> 7, q = idx & (D - 1);
    w1c[q * W1S + p] = f2bf((p > q) ? W1[idx] : 0.f);
  }
  __syncthreads();
  const int lane = tid & 63;
  const int m = lane & 15;
  const int row = blockIdx.x * FRPB + (tid >> 4);
  const float* __restrict__ xp = x + (size_t)row * D;
  const float* __restrict__ wmup = Wmu + m * 8;
  const float* __restrict__ wlsp = Wls + m * 8;
  const uint16_t* __restrict__ w1p = w1c + m * 8;
  f2 A0, A1, A2, A3;
  {
    const f4 t0 = *(const f4*)(b1 + m * 8);
    const f4 t1 = *(const f4*)(b1 + m * 8 + 4);
    A0 = t0.xy; A1 = t0.zw; A2 = t1.xy; A3 = t1.zw;
  }
  f2 mk0 = (f2)0.f, mk1 = (f2)0.f, mk2 = (f2)0.f, mk3 = (f2)0.f;
  float zr0 = 0, zr1 = 0, zr2 = 0, zr3 = 0, zr4 = 0, zr5 = 0, zr6 = 0, zr7 = 0;
  float ldj = 0.f;
  f4 wmA0 = *(const f4*)(wmup);
  f4 wmA1 = *(const f4*)(wmup + 4);
  f4 wlA0 = *(const f4*)(wlsp);
  f4 wlA1 = *(const f4*)(wlsp + 4);
  f4 wmB0 = *(const f4*)(wmup + D);
  f4 wmB1 = *(const f4*)(wmup + D + 4);
  f4 wlB0 = *(const f4*)(wlsp + D);
  f4 wlB1 = *(const f4*)(wlsp + D + 4);
  f4 x4a = *(const f4*)(xp);
  f4 x4b;
  for (int ib = 0; ib < 16; ++ib) {
    const int i0 = ib * 8;
    const bool own = (m == ib);
    x4b = *(const f4*)(xp + i0 + 4);
    FSTEP(i0 + 0, x4a.x, zr0, mk0.x, wmA0, wmA1, wlA0, wlA1);
    FSTEP(i0 + 1, x4a.y, zr1, mk0.y, wmB0, wmB1, wlB0, wlB1);
    FSTEP(i0 + 2, x4a.z, zr2, mk1.x, wmA0, wmA1, wlA0, wlA1);
    FSTEP(i0 + 3, x4a.w, zr3, mk1.y, wmB0, wmB1, wlB0, wlB1);
    {
      const int nx = (i0 + 8 < D) ? i0 + 8 : D - 4;
      x4a = *(const f4*)(xp + nx);
    }
    FSTEP(i0 + 4, x4b.x, zr4, mk2.x, wmA0, wmA1, wlA0, wlA1);
    FSTEP(i0 + 5, x4b.y, zr5, mk2.y, wmB0, wmB1, wlB0, wlB1);
    FSTEP(i0 + 6, x4b.z, zr6, mk3.x, wmA0, wmA1, wlA0, wlA1);
    FSTEP(i0 + 7, x4b.w, zr7, mk3.y, wmB0, wmB1, wlB0, wlB1);
  }
  f4 o0, o1;
  o0.x = zr0; o0.y = zr1; o0.z = zr2; o0.w = zr3;
  o1.x = zr4; o1.y = zr5; o1.z = zr6; o1.w = zr7;
  float* zo = out + (size_t)row * D + m * 8;
  *(f4*)(zo) = o0;
  *(f4*)(zo + 4) = o1;
  if (m == 0) out[(size_t)B * D + row] = ldj;
}

extern "C" void kernel_launch(void* const* d_in, const int* in_sizes, int n_in,
                              void* d_out, int out_size, void* d_ws, size_t ws_size,
                              hipStream_t stream) {
  const float* x   = (const float*)d_in[0];
  const float* W1  = (const float*)d_in[1];
  const float* b1  = (const float*)d_in[2];
  const float* Wmu = (const float*)d_in[3];
  const float* bmu = (const float*)d_in[4];
  const float* Wls = (const float*)d_in[5];
  const float* bls = (const float*)d_in[6];
  float* out = (float*)d_out;

  const int B = in_sizes[0] / D;  // 8192

  if (ws_size >= WS_NEED) {
    iaf_prep<<<(D * D + 255) / 256, 256, 0, stream>>>(W1, Wmu, Wls, (uint16_t*)d_ws);
    const int grid = (B + RPB - 1) / RPB;  // 256
    iaf_main<<<grid, NTHR, 0, stream>>>(x, b1, bmu, bls, (const uint16_t*)d_ws, out, B);
  } else {
    const int grid = (B + FRPB - 1) / FRPB;  // 512
    iaf_fb<<<grid, FNTHR, 0, stream>>>(x, W1, b1, Wmu, bmu, Wls, bls, out, B);
  }
}

// Round 10
// 38.353 us; speedup vs baseline: 2.0529x; 1.0511x over previous
//
#include <hip/hip_runtime.h>
#include <stdint.h>

#define D 128
#define NTHR 512
#define RPB 32  // rows per block: 8 waves x 4 rows(16 lanes each)

typedef float f2 __attribute__((ext_vector_type(2)));
typedef float f4 __attribute__((ext_vector_type(4)));
typedef __fp16 h2 __attribute__((ext_vector_type(2)));

// ws layout (uint16 elements): wmu[D*D] | wls[D*D] | w1t[D*D]
#define WS_NEED (size_t)(D * D * 6)

__device__ __forceinline__ h2 bch2(uint32_t u) { return __builtin_bit_cast(h2, u); }
__device__ __forceinline__ float fdot2f(h2 a, h2 b, float c) {
  return __builtin_amdgcn_fdot2(a, b, c, false);
}
template <int CTRL>
__device__ __forceinline__ float dppmov(float v) {
  return __int_as_float(
      __builtin_amdgcn_update_dpp(0, __float_as_int(v), CTRL, 0xf, 0xf, true));
}
#define DPP_ADD(v, ctrl) (v) += dppmov<(ctrl)>((v))

// ================= prep: mask + transpose + f16-pack into ws =================
__global__ __launch_bounds__(256)
void iaf_prep(const float* __restrict__ W1, const float* __restrict__ Wmu,
              const float* __restrict__ Wls, uint16_t* __restrict__ ws) {
  const int idx = blockIdx.x * 256 + threadIdx.x;
  if (idx >= D * D) return;
  const int i = idx >> 7, j = idx & (D - 1);
  const __fp16 mu = (__fp16)((j < i) ? Wmu[idx] : 0.f);
  const __fp16 ls = (__fp16)((j < i) ? Wls[idx] : 0.f);
  const __fp16 w1 = (__fp16)((j > i) ? W1[j * D + i] : 0.f);  // column i of W1
  ws[idx] = __builtin_bit_cast(uint16_t, mu);
  ws[D * D + idx] = __builtin_bit_cast(uint16_t, ls);
  ws[2 * D * D + idx] = __builtin_bit_cast(uint16_t, w1);
}

// ===== main: 16 lanes/row, LDS f16 weights, all-DPP reduce, reg double-buffer =====
// Load 4 steps' operands (weights/x/biases) for iteration IT into buffer P##.
#define LOAD4(P, IT)                                                  \
  {                                                                   \
    const int ii_ = (IT) * 4;                                         \
    if (m8 < ii_ + 4) { /* lanes feeding the dots */                  \
      P##wm0 = *(const uint4*)(wmu_s + (ii_ + 0) * D + m8);           \
      P##wm1 = *(const uint4*)(wmu_s + (ii_ + 1) * D + m8);           \
      P##wm2 = *(const uint4*)(wmu_s + (ii_ + 2) * D + m8);           \
      P##wm3 = *(const uint4*)(wmu_s + (ii_ + 3) * D + m8);           \
      P##wl0 = *(const uint4*)(wls_s + (ii_ + 0) * D + m8);           \
      P##wl1 = *(const uint4*)(wls_s + (ii_ + 1) * D + m8);           \
      P##wl2 = *(const uint4*)(wls_s + (ii_ + 2) * D + m8);           \
      P##wl3 = *(const uint4*)(wls_s + (ii_ + 3) * D + m8);           \
    }                                                                 \
    if (m8 + 7 > ii_) { /* lanes feeding the updates */               \
      P##w10 = *(const uint4*)(w1t_s + (ii_ + 0) * D + m8);           \
      P##w11 = *(const uint4*)(w1t_s + (ii_ + 1) * D + m8);           \
      P##w12 = *(const uint4*)(w1t_s + (ii_ + 2) * D + m8);           \
      P##w13 = *(const uint4*)(w1t_s + (ii_ + 3) * D + m8);           \
    }                                                                 \
    P##x = *(const f4*)(xs_row + ii_);                                \
    P##b01 = *(const f4*)(bias2 + 2 * ii_);     /* {bm,bl}i, i+1 */   \
    P##b23 = *(const f4*)(bias2 + 2 * ii_ + 4); /* {bm,bl}i+2,i+3 */  \
  }

#define STEPX(I, WM, WL, WV, XE, BMU, BLS, ZRI)                         \
  {                                                                     \
    float mu_p = 0.f, ls_p = 0.f;                                       \
    if (m8 < (I)) { /* garbage-safe: exec-masked, zero-masked wts */    \
      const h2 h01_ = __builtin_elementwise_max(a01, hz);               \
      const h2 h23_ = __builtin_elementwise_max(a23, hz);               \
      const h2 h45_ = __builtin_elementwise_max(a45, hz);               \
      const h2 h67_ = __builtin_elementwise_max(a67, hz);               \
      mu_p = fdot2f(h01_, bch2(WM.x), 0.f);                             \
      mu_p = fdot2f(h23_, bch2(WM.y), mu_p);                            \
      mu_p = fdot2f(h45_, bch2(WM.z), mu_p);                            \
      mu_p = fdot2f(h67_, bch2(WM.w), mu_p);                            \
      ls_p = fdot2f(h01_, bch2(WL.x), 0.f);                             \
      ls_p = fdot2f(h23_, bch2(WL.y), ls_p);                            \
      ls_p = fdot2f(h45_, bch2(WL.z), ls_p);                            \
      ls_p = fdot2f(h67_, bch2(WL.w), ls_p);                            \
    }                                                                   \
    /* folded 16-lane reduce: lanes 0-7 carry mu, 8-15 carry ls */      \
    float fold = hi ? ls_p : mu_p;                                      \
    fold += dppmov<0x128>(hi ? mu_p : ls_p); /* row_ror:8 == xor8 */    \
    DPP_ADD(fold, 0xB1);  /* quad_perm xor1 */                          \
    DPP_ADD(fold, 0x4E);  /* quad_perm xor2 */                          \
    DPP_ADD(fold, 0x141); /* row_half_mirror */                         \
    const float other = dppmov<0x128>(fold);                            \
    const float mu_t = (hi ? other : fold) + (BMU);                     \
    const float ls_t = (hi ? fold : other) + (BLS);                     \
    const float zi = fmaf((XE), __expf(ls_t), mu_t); /* replicated */   \
    ldj += ls_t;                                                        \
    if (m == ((I) >> 3)) ZRI = zi;                                      \
    if (m8 + 7 > (I)) {                                                 \
      const h2 z2_ = __builtin_amdgcn_cvt_pkrtz(zi, zi);                \
      a01 = __builtin_elementwise_fma(z2_, bch2(WV.x), a01);            \
      a23 = __builtin_elementwise_fma(z2_, bch2(WV.y), a23);            \
      a45 = __builtin_elementwise_fma(z2_, bch2(WV.z), a45);            \
      a67 = __builtin_elementwise_fma(z2_, bch2(WV.w), a67);            \
    }                                                                   \
  }

__global__ __launch_bounds__(NTHR, 2)
void iaf_main(const float* __restrict__ x, const float* __restrict__ b1,
              const float* __restrict__ bmu, const float* __restrict__ bls,
              const uint16_t* __restrict__ ws, float* __restrict__ out, int B) {
  __shared__ uint16_t wmu_s[D * D];  // 32KB each
  __shared__ uint16_t wls_s[D * D];
  __shared__ uint16_t w1t_s[D * D];
  __shared__ float xs[RPB][D + 4];   // padded: 16B-aligned rows, banks spread
  __shared__ float bias2[2 * D];     // {bmu[i], bls[i]} interleaved

  const int tid = threadIdx.x;
  const int r0 = blockIdx.x * RPB;
  // ---- stage weights ws -> LDS (b128 copies) ----
  {
    const uint4* s0 = (const uint4*)(ws);
    const uint4* s1 = (const uint4*)(ws + D * D);
    const uint4* s2 = (const uint4*)(ws + 2 * D * D);
    uint4* d0 = (uint4*)wmu_s;
    uint4* d1 = (uint4*)wls_s;
    uint4* d2 = (uint4*)w1t_s;
#pragma unroll
    for (int k = 0; k < 4; ++k) {
      d0[tid + k * NTHR] = s0[tid + k * NTHR];
      d1[tid + k * NTHR] = s1[tid + k * NTHR];
      d2[tid + k * NTHR] = s2[tid + k * NTHR];
    }
  }
  // ---- stage x rows + biases ----
  {
    const int r = tid >> 4;
    const int c = (tid & 15) * 8;
    const f4 t0 = *(const f4*)(x + (size_t)(r0 + r) * D + c);
    const f4 t1 = *(const f4*)(x + (size_t)(r0 + r) * D + c + 4);
    *(f4*)(&xs[r][c]) = t0;
    *(f4*)(&xs[r][c + 4]) = t1;
    if (tid < D) {
      bias2[2 * tid] = bmu[tid];
      bias2[2 * tid + 1] = bls[tid];
    }
  }

  const int m = tid & 15;
  const int m8 = m << 3;
  const bool hi = (m & 8) != 0;
  const int row = r0 + (tid >> 4);
  const float* __restrict__ xs_row = xs[tid >> 4];

  // a = b1 chunk, in f16 pairs
  h2 a01, a23, a45, a67;
  {
    const f4 t0 = *(const f4*)(b1 + m8);
    const f4 t1 = *(const f4*)(b1 + m8 + 4);
    a01 = __builtin_amdgcn_cvt_pkrtz(t0.x, t0.y);
    a23 = __builtin_amdgcn_cvt_pkrtz(t0.z, t0.w);
    a45 = __builtin_amdgcn_cvt_pkrtz(t1.x, t1.y);
    a67 = __builtin_amdgcn_cvt_pkrtz(t1.z, t1.w);
  }
  const h2 hz = bch2(0u);
  float zr[8];
  float ldj = 0.f;

  // double-buffer registers (zero-init once; exec-masked loads leave some lanes stale,
  // which is safe: consumers are exec-masked identically)
  uint4 Awm0 = {}, Awm1 = {}, Awm2 = {}, Awm3 = {};
  uint4 Awl0 = {}, Awl1 = {}, Awl2 = {}, Awl3 = {};
  uint4 Aw10 = {}, Aw11 = {}, Aw12 = {}, Aw13 = {};
  uint4 Bwm0 = {}, Bwm1 = {}, Bwm2 = {}, Bwm3 = {};
  uint4 Bwl0 = {}, Bwl1 = {}, Bwl2 = {}, Bwl3 = {};
  uint4 Bw10 = {}, Bw11 = {}, Bw12 = {}, Bw13 = {};
  f4 Ax = {}, Bx = {}, Ab01 = {}, Ab23 = {}, Bb01 = {}, Bb23 = {};

  __syncthreads();

  LOAD4(A, 0)

#pragma unroll 1
  for (int it = 0; it < 32; it += 2) {
    const int i0 = it * 4;
    LOAD4(B, it + 1)  // in flight while computing A
    STEPX(i0 + 0, Awm0, Awl0, Aw10, Ax.x, Ab01.x, Ab01.y, zr[0])
    STEPX(i0 + 1, Awm1, Awl1, Aw11, Ax.y, Ab01.z, Ab01.w, zr[1])
    STEPX(i0 + 2, Awm2, Awl2, Aw12, Ax.z, Ab23.x, Ab23.y, zr[2])
    STEPX(i0 + 3, Awm3, Awl3, Aw13, Ax.w, Ab23.z, Ab23.w, zr[3])
    const int nit = (it + 2 < 32) ? it + 2 : 31;
    LOAD4(A, nit)     // in flight while computing B
    STEPX(i0 + 4, Bwm0, Bwl0, Bw10, Bx.x, Bb01.x, Bb01.y, zr[4])
    STEPX(i0 + 5, Bwm1, Bwl1, Bw11, Bx.y, Bb01.z, Bb01.w, zr[5])
    STEPX(i0 + 6, Bwm2, Bwl2, Bw12, Bx.z, Bb23.x, Bb23.y, zr[6])
    STEPX(i0 + 7, Bwm3, Bwl3, Bw13, Bx.w, Bb23.z, Bb23.w, zr[7])
  }

  // ---- stores: lane m owns columns 8m..8m+7 of its row ----
  f4 o0, o1;
  o0.x = zr[0]; o0.y = zr[1]; o0.z = zr[2]; o0.w = zr[3];
  o1.x = zr[4]; o1.y = zr[5]; o1.z = zr[6]; o1.w = zr[7];
  float* zo = out + (size_t)row * D + m8;
  *(f4*)(zo) = o0;
  *(f4*)(zo + 4) = o1;
  if (m == 0) out[(size_t)B * D + row] = ldj;
}

// ================= fallback (proven R3 kernel, if ws too small) =================
#define FNTHR 256
#define FRPB 16
#define W1S 136
__device__ __forceinline__ uint16_t f2bf(float f) {
  uint32_t u = __float_as_uint(f);
  u += 0x7fffu + ((u >> 16) & 1u);
  return (uint16_t)(u >> 16);
}
__device__ __forceinline__ f2 unpk(uint32_t u) {
  f2 r;
  r.x = __uint_as_float(u << 16);
  r.y = __uint_as_float(u & 0xffff0000u);
  return r;
}
#define RED16F(v)      \
  do {                 \
    DPP_ADD(v, 0xB1);  \
    DPP_ADD(v, 0x4E);  \
    DPP_ADD(v, 0x124); \
    DPP_ADD(v, 0x128); \
  } while (0)
#define FSTEP(I, XE, ZRE, MKE, WM0, WM1, WL0, WL1)                  \
  {                                                                 \
    const float bmu_i = bmu[(I)];                                   \
    const float bls_i = bls[(I)];                                   \
    const f2 h0 = __builtin_elementwise_max(A0, (f2)0.f);           \
    const f2 h1 = __builtin_elementwise_max(A1, (f2)0.f);           \
    const f2 h2_ = __builtin_elementwise_max(A2, (f2)0.f);          \
    const f2 h3 = __builtin_elementwise_max(A3, (f2)0.f);           \
    const f2 q0 = h0 * mk0, q1 = h1 * mk1;                          \
    const f2 q2 = h2_ * mk2, q3 = h3 * mk3;                         \
    f2 am = q0 * WM0.xy;                                            \
    f2 al = q0 * WL0.xy;                                            \
    am = __builtin_elementwise_fma(q1, WM0.zw, am);                 \
    al = __builtin_elementwise_fma(q1, WL0.zw, al);                 \
    am = __builtin_elementwise_fma(q2, WM1.xy, am);                 \
    al = __builtin_elementwise_fma(q2, WL1.xy, al);                 \
    am = __builtin_elementwise_fma(q3, WM1.zw, am);                 \
    al = __builtin_elementwise_fma(q3, WL1.zw, al);                 \
    float mu_p = am.x + am.y;                                       \
    float ls_p = al.x + al.y;                                       \
    {                                                               \
      const int pfr = ((I) + 2 < D) ? (I) + 2 : D - 1;              \
      WM0 = *(const f4*)(wmup + pfr * D);                           \
      WM1 = *(const f4*)(wmup + pfr * D + 4);                       \
      WL0 = *(const f4*)(wlsp + pfr * D);                           \
      WL1 = *(const f4*)(wlsp + pfr * D + 4);                       \
    }                                                               \
    RED16F(mu_p);                                                   \
    RED16F(ls_p);                                                   \
    const float mu_t = mu_p + bmu_i;                                \
    const float ls_t = ls_p + bls_i;                                \
    const float zi = fmaf((XE), __expf(ls_t), mu_t);                \
    ldj += ls_t;                                                    \
    const uint4 wv = *(const uint4*)(w1p + (I)*W1S);                \
    if (own) {                                                      \
      ZRE = zi;                                                     \
      MKE = 1.f;                                                    \
    }                                                               \
    f2 zz;                                                          \
    zz.x = zi;                                                      \
    zz.y = zi;                                                      \
    A0 = __builtin_elementwise_fma(zz, unpk(wv.x), A0);             \
    A1 = __builtin_elementwise_fma(zz, unpk(wv.y), A1);             \
    A2 = __builtin_elementwise_fma(zz, unpk(wv.z), A2);             \
    A3 = __builtin_elementwise_fma(zz, unpk(wv.w), A3);             \
  }

__global__ __launch_bounds__(FNTHR, 2)
void iaf_fb(const float* __restrict__ x, const float* __restrict__ W1,
            const float* __restrict__ b1, const float* __restrict__ Wmu,
            const float* __restrict__ bmu, const float* __restrict__ Wls,
            const float* __restrict__ bls, float* __restrict__ out, int B) {
  __shared__ uint16_t w1c[D * W1S];
  const int tid = threadIdx.x;
  for (int idx = tid; idx < D * D; idx += FNTHR) {
    const int p = idx >> 7, q = idx & (D - 1);
    w1c[q * W1S + p] = f2bf((p > q) ? W1[idx] : 0.f);
  }
  __syncthreads();
  const int lane = tid & 63;
  const int m = lane & 15;
  const int row = blockIdx.x * FRPB + (tid >> 4);
  const float* __restrict__ xp = x + (size_t)row * D;
  const float* __restrict__ wmup = Wmu + m * 8;
  const float* __restrict__ wlsp = Wls + m * 8;
  const uint16_t* __restrict__ w1p = w1c + m * 8;
  f2 A0, A1, A2, A3;
  {
    const f4 t0 = *(const f4*)(b1 + m * 8);
    const f4 t1 = *(const f4*)(b1 + m * 8 + 4);
    A0 = t0.xy; A1 = t0.zw; A2 = t1.xy; A3 = t1.zw;
  }
  f2 mk0 = (f2)0.f, mk1 = (f2)0.f, mk2 = (f2)0.f, mk3 = (f2)0.f;
  float zr0 = 0, zr1 = 0, zr2 = 0, zr3 = 0, zr4 = 0, zr5 = 0, zr6 = 0, zr7 = 0;
  float ldj = 0.f;
  f4 wmA0 = *(const f4*)(wmup);
  f4 wmA1 = *(const f4*)(wmup + 4);
  f4 wlA0 = *(const f4*)(wlsp);
  f4 wlA1 = *(const f4*)(wlsp + 4);
  f4 wmB0 = *(const f4*)(wmup + D);
  f4 wmB1 = *(const f4*)(wmup + D + 4);
  f4 wlB0 = *(const f4*)(wlsp + D);
  f4 wlB1 = *(const f4*)(wlsp + D + 4);
  f4 x4a = *(const f4*)(xp);
  f4 x4b;
  for (int ib = 0; ib < 16; ++ib) {
    const int i0 = ib * 8;
    const bool own = (m == ib);
    x4b = *(const f4*)(xp + i0 + 4);
    FSTEP(i0 + 0, x4a.x, zr0, mk0.x, wmA0, wmA1, wlA0, wlA1);
    FSTEP(i0 + 1, x4a.y, zr1, mk0.y, wmB0, wmB1, wlB0, wlB1);
    FSTEP(i0 + 2, x4a.z, zr2, mk1.x, wmA0, wmA1, wlA0, wlA1);
    FSTEP(i0 + 3, x4a.w, zr3, mk1.y, wmB0, wmB1, wlB0, wlB1);
    {
      const int nx = (i0 + 8 < D) ? i0 + 8 : D - 4;
      x4a = *(const f4*)(xp + nx);
    }
    FSTEP(i0 + 4, x4b.x, zr4, mk2.x, wmA0, wmA1, wlA0, wlA1);
    FSTEP(i0 + 5, x4b.y, zr5, mk2.y, wmB0, wmB1, wlB0, wlB1);
    FSTEP(i0 + 6, x4b.z, zr6, mk3.x, wmA0, wmA1, wlA0, wlA1);
    FSTEP(i0 + 7, x4b.w, zr7, mk3.y, wmB0, wmB1, wlB0, wlB1);
  }
  f4 o0, o1;
  o0.x = zr0; o0.y = zr1; o0.z = zr2; o0.w = zr3;
  o1.x = zr4; o1.y = zr5; o1.z = zr6; o1.w = zr7;
  float* zo = out + (size_t)row * D + m * 8;
  *(f4*)(zo) = o0;
  *(f4*)(zo + 4) = o1;
  if (m == 0) out[(size_t)B * D + row] = ldj;
}

extern "C" void kernel_launch(void* const* d_in, const int* in_sizes, int n_in,
                              void* d_out, int out_size, void* d_ws, size_t ws_size,
                              hipStream_t stream) {
  const float* x   = (const float*)d_in[0];
  const float* W1  = (const float*)d_in[1];
  const float* b1  = (const float*)d_in[2];
  const float* Wmu = (const float*)d_in[3];
  const float* bmu = (const float*)d_in[4];
  const float* Wls = (const float*)d_in[5];
  const float* bls = (const float*)d_in[6];
  float* out = (float*)d_out;

  const int B = in_sizes[0] / D;  // 8192

  if (ws_size >= WS_NEED) {
    iaf_prep<<<(D * D + 255) / 256, 256, 0, stream>>>(W1, Wmu, Wls, (uint16_t*)d_ws);
    const int grid = (B + RPB - 1) / RPB;  // 256
    iaf_main<<<grid, NTHR, 0, stream>>>(x, b1, bmu, bls, (const uint16_t*)d_ws, out, B);
  } else {
    const int grid = (B + FRPB - 1) / FRPB;  // 512
    iaf_fb<<<grid, FNTHR, 0, stream>>>(x, W1, b1, Wmu, bmu, Wls, bls, out, B);
  }
}